// Round 12
// baseline (216.656 us; speedup 1.0000x reference)
//
#include <hip/hip_runtime.h>
#include <hip/hip_bf16.h>

typedef long long i64;
typedef unsigned int uint;
using u16 = unsigned short;
using f32x4  = __attribute__((ext_vector_type(4))) float;
using bf16x8 = __attribute__((ext_vector_type(8))) short;
using u32x4  = __attribute__((ext_vector_type(4))) uint;
using u16x4  = __attribute__((ext_vector_type(4))) u16;

// 0.125 (attention scaling) * log2(e): folded into q bf16 copy so softmax
// uses exp2 directly. Softmax is invariant to the base change.
#define QSCALE 0.18033688011112042f

__device__ __forceinline__ u16 f2b(float x) {   // f32 -> bf16 RNE
    uint u = __float_as_uint(x);
    return (u16)((u + 0x7FFFu + ((u >> 16) & 1u)) >> 16);
}
__device__ __forceinline__ uint cvt_pk_bf16(float lo, float hi) {
    uint r;
    asm("v_cvt_pk_bf16_f32 %0, %1, %2" : "=v"(r) : "v"(lo), "v"(hi));
    return r;   // low 16 bits = bf16(lo), high = bf16(hi)
}

// ---------------------------------------------------------------------------
// conv_pad: f32 [M_valid x K_valid] (row stride s_row) -> bf16 [Mpad][Kpad],
// zero-padded. Kpad = 1<<kshift.
// ---------------------------------------------------------------------------
__global__ __launch_bounds__(256) void conv_pad(
    const float* __restrict__ src, u16* __restrict__ dst,
    int M_valid, int K_valid, int kshift, int s_row)
{
    i64 i = (i64)blockIdx.x * 256 + threadIdx.x;   // over Mpad*Kpad/4
    int m = (int)(i >> (kshift - 2));
    int k = ((int)(i & ((1 << (kshift - 2)) - 1))) << 2;
    u16x4 hv;
    #pragma unroll
    for (int j = 0; j < 4; ++j) {
        int kk = k + j;
        float x = (m < M_valid && kk < K_valid) ? src[(i64)m * s_row + kk] : 0.f;
        hv[j] = f2b(x);
    }
    *(u16x4*)(dst + ((i64)m << kshift) + k) = hv;
}

// ---------------------------------------------------------------------------
// conv_wout_perm: dst[n][kp] = bf16(w_out[n][(kp&63)*16 + (kp>>6)])
// ---------------------------------------------------------------------------
__global__ __launch_bounds__(256) void conv_wout_perm(
    const float* __restrict__ w, u16* __restrict__ dst)
{
    int i = blockIdx.x * 256 + threadIdx.x;        // over 1024*1024/4
    int n = i >> 8, kp4 = (i & 255) << 2;
    u16x4 hv;
    #pragma unroll
    for (int j = 0; j < 4; ++j) {
        int kp = kp4 + j;
        hv[j] = f2b(w[((i64)n << 10) + ((kp & 63) << 4) + (kp >> 6)]);
    }
    *(u16x4*)(dst + ((i64)n << 10) + kp4) = hv;
}

// ---------------------------------------------------------------------------
// build_kvA: A-panel for the kv-GEMM, transposed to l-contiguous bf16.
// rows 0..1023: A[d][l] = X[l][b][d]; rows 1024..1535: A[1024+c][l]=qp[(l4+b)c]
// ---------------------------------------------------------------------------
__global__ __launch_bounds__(256) void build_kvA(
    const float* __restrict__ X, const float* __restrict__ qp,
    u16* __restrict__ dst)
{
    const int b = blockIdx.z, r0 = blockIdx.y * 64, l0 = blockIdx.x * 64;
    const int tid = threadIdx.x;
    __shared__ float ts[64][65];
    #pragma unroll
    for (int t = 0; t < 16; ++t) {
        int idx = t * 256 + tid;
        int ch = idx & 63, lr = idx >> 6;
        int lg = l0 + lr;
        float v = 0.f;
        if (lg < 2046) {
            if (r0 < 1024) v = X[(i64)lg * 4096 + b * 1024 + (r0 + ch)];
            else           v = qp[((i64)lg * 4 + b) * 512 + (r0 - 1024 + ch)];
        }
        ts[lr][ch] = v;
    }
    __syncthreads();
    #pragma unroll
    for (int t = 0; t < 16; ++t) {
        int idx = t * 256 + tid;
        int ll = idx & 63, rl = idx >> 6;
        dst[((i64)b * 1536 + r0 + rl) * 2048 + l0 + ll] = f2b(ts[ll][rl]);
    }
}

// ---------------------------------------------------------------------------
// Plain-bf16 MFMA GEMM: C[m][n] = sum_k A[m][k]*B[n][k]. 128x128 tile, BK=32,
// 4 waves (2x2 of 64x64). LDS XOR-swizzled ((r&3)<<4). Epilogue by MODE.
//  MODE 1 v-sigma2: vT slot for p encodes the swapped-QK in-register P
//  distribution: slot(p) = (p&~31) + ((p>>2)&3)*8 + (p&3) + ((p>>4)&1)*4.
// ---------------------------------------------------------------------------
template<int MODE>
__global__ __launch_bounds__(256) void gemm_bf16(
    const u16* __restrict__ A, i64 a_bs,
    const u16* __restrict__ Bm,
    float* __restrict__ C, const float* __restrict__ bias,
    u16* __restrict__ x0, u16* __restrict__ x1,
    int Krow, int KT, int M_valid)
{
    __shared__ __align__(16) u16 As[4096], Bs[4096];   // 128 rows x 32 k each
    const int tid = threadIdx.x, lane = tid & 63, w = tid >> 6;
    const int fr = lane & 15, g = lane >> 4;
    const int nb = blockIdx.x, mb = blockIdx.y, bz = blockIdx.z;

    const u16* src = (w < 2)
        ? (A + (i64)bz * a_bs + ((i64)mb * 128 + (w & 1) * 64) * Krow)
        : (Bm + ((i64)nb * 128 + (w & 1) * 64) * Krow);
    u16* dstb = (w < 2) ? As : Bs;
    const int R0 = (w & 1) * 64;
    const int lr = lane >> 2, lcg = lane & 3;          // 16 rows x 4 chunks

    f32x4 acc[4][4];
    #pragma unroll
    for (int i = 0; i < 4; ++i)
        #pragma unroll
        for (int j = 0; j < 4; ++j)
            acc[i][j] = (f32x4){0.f, 0.f, 0.f, 0.f};

    u32x4 st[4];
    #pragma unroll
    for (int it = 0; it < 4; ++it)
        st[it] = *(const u32x4*)(src + (i64)(it * 16 + lr) * Krow + lcg * 8);

    const int wr = (w >> 1) * 64, wc = (w & 1) * 64;

    for (int kt = 0; kt < KT; ++kt) {
        __syncthreads();
        #pragma unroll
        for (int it = 0; it < 4; ++it) {
            int R = R0 + it * 16 + lr;
            *(u32x4*)((char*)dstb + R * 64 + ((lcg ^ (R & 3)) << 4)) = st[it];
        }
        __syncthreads();
        if (kt + 1 < KT) {
            #pragma unroll
            for (int it = 0; it < 4; ++it)
                st[it] = *(const u32x4*)(src + (i64)(it * 16 + lr) * Krow
                                             + (kt + 1) * 32 + lcg * 8);
        }
        bf16x8 ah[4], bh[4];
        #pragma unroll
        for (int mi = 0; mi < 4; ++mi) {
            int rr = wr + mi * 16 + fr;
            ah[mi] = *(const bf16x8*)((const char*)As + rr * 64 + ((g * 16) ^ ((rr & 3) << 4)));
        }
        #pragma unroll
        for (int ni = 0; ni < 4; ++ni) {
            int rr = wc + ni * 16 + fr;
            bh[ni] = *(const bf16x8*)((const char*)Bs + rr * 64 + ((g * 16) ^ ((rr & 3) << 4)));
        }
        #pragma unroll
        for (int mi = 0; mi < 4; ++mi)
            #pragma unroll
            for (int ni = 0; ni < 4; ++ni)
                acc[mi][ni] = __builtin_amdgcn_mfma_f32_16x16x32_bf16(
                    ah[mi], bh[ni], acc[mi][ni], 0, 0, 0);
    }

    #pragma unroll
    for (int mi = 0; mi < 4; ++mi)
        #pragma unroll
        for (int ni = 0; ni < 4; ++ni) {
            int gm0 = mb * 128 + wr + mi * 16 + g * 4;
            int gn  = nb * 128 + wc + ni * 16 + fr;
            #pragma unroll
            for (int r = 0; r < 4; ++r) {
                int gm = gm0 + r;
                float val = acc[mi][ni][r];
                if (MODE == 0) {
                    val += bias[gn];
                    C[(i64)gm * 512 + gn] = val;
                    x0[(i64)gm * 512 + gn] = f2b(val * QSCALE);
                } else if (MODE == 1) {
                    if (gm < 1024) {   // v: channel = e*16+h, sigma2 p-slot
                        int e = gm >> 4, hh = gm & 15;
                        i64 s = ((i64)(bz * 16 + hh) * 64 + e) * 1024
                              + (gn & ~31) + (((gn >> 2) & 3) << 3)
                              + (gn & 3) + (((gn >> 4) & 1) << 2);
                        x1[s] = f2b(val);
                    } else {           // k: channel-1024 = d*16+h
                        int c2 = gm - 1024, d = c2 >> 4, hh = c2 & 15;
                        x0[((i64)(bz * 16 + hh) * 1024 + gn) * 32 + d] = f2b(val);
                    }
                } else {
                    if (gm < M_valid)
                        C[(i64)bz * 1024 + (i64)gm * 4096 + gn] = val + bias[gn];
                }
            }
        }
}

// ---------------------------------------------------------------------------
// MFMA attention v7: swapped QK^T -> P stays IN REGISTERS (no P LDS at all).
// T = mfma(A=K_frag, B=Q_frag): C col=lane&15=l, row=4g+r=p. Each lane holds
// P of its own output row l=fr at p = nf*16+4g+r; exp2+cvt_pk pack those
// directly into the PV A-fragment words. vT's sigma2 (built in the kv-GEMM
// epilogue) gives the V fragment the SAME per-lane p permutation, so PV is
// correct by the consistent-k-permutation principle.
// Grid = 1024 XCD-affine blocks (16 consecutive share one bh -> L2-resident
// K/V). Block = 4 waves x 32 rows. K cooperatively staged in LDS (dbuf, 80B
// pitch, one barrier/iter); V direct from L2. setprio(1) around MFMA.
// ---------------------------------------------------------------------------
__global__ __launch_bounds__(256) void attn_mfma(
    const u16* __restrict__ qb, const u16* __restrict__ kT,
    const u16* __restrict__ vT, u16* __restrict__ attA)
{
    const int g0 = blockIdx.x;
    const int xcd = g0 & 7, sub = g0 >> 3;
    const int lblk = sub & 15;                  // same bh for 16 consecutive
    const int bh = xcd + ((sub >> 4) << 3);     // 8 bh per XCD
    const int b = bh >> 4, h = bh & 15;
    const int tid = threadIdx.x, lane = tid & 63, w = tid >> 6;   // 0..3
    const int fr = lane & 15, g = lane >> 4;
    const int l0 = lblk * 128 + w * 32;

    __shared__ __align__(16) u16 kbuf[2][2560];    // 64 rows x 40 u16 (80B pitch)

    // Q fragments (B operand): n = l = fr within tile mf, d-slots g*8..
    bf16x8 aq[2];
    #pragma unroll
    for (int mf = 0; mf < 2; ++mf)
        aq[mf] = *(const bf16x8*)(qb + ((i64)((l0 + mf * 16 + fr) * 4 + b) * 512
                                        + h * 32 + g * 8));   // row = l*4+b

    const u16* vbase = vT + (i64)bh * 65536;
    const f32x4 zf = {0.f, 0.f, 0.f, 0.f};

    // K staging lane constants: row kr (0..63), 16B chunk kc (0..3)
    const int kr = tid >> 2, kc = tid & 3;
    const u16* ksrc = kT + (i64)bh * 32768 + kr * 32 + kc * 8;        // +t*2048
    char* kdst = (char*)&kbuf[0][0] + kr * 80 + kc * 16;              // +buf*5120

    // prologue: stage K(0)
    *(u32x4*)(kdst) = *(const u32x4*)(ksrc);
    __syncthreads();

    float l_part[2] = {0.f, 0.f};
    f32x4 o[2][4];
    #pragma unroll
    for (int mf = 0; mf < 2; ++mf)
        #pragma unroll
        for (int nf = 0; nf < 4; ++nf)
            o[mf][nf] = zf;

    for (int t = 0; t < 16; ++t) {
        const int cur = t & 1;
        const int tn = (t < 15) ? t + 1 : 15;

        // 1. issue next K tile global load (consumed by ds_write below)
        u32x4 knx = *(const u32x4*)(ksrc + tn * 2048);

        // 2. V(t) loads (direct from L2, sigma2 layout; latency covered by QK+exp)
        bf16x8 vf[8];
        #pragma unroll
        for (int ks = 0; ks < 2; ++ks)
            #pragma unroll
            for (int nf = 0; nf < 4; ++nf)
                vf[ks * 4 + nf] = *(const bf16x8*)(vbase + (i64)(nf * 16 + fr) * 1024
                                                         + t * 64 + ks * 32 + g * 8);

        // 3. QK(t), swapped operands: T[mf][nf] rows=p, cols=l
        const char* kc_ = (const char*)&kbuf[cur][0];
        f32x4 s[2][4];
        __builtin_amdgcn_s_setprio(1);
        #pragma unroll
        for (int nf = 0; nf < 4; ++nf) {
            bf16x8 ak = *(const bf16x8*)(kc_ + (nf * 16 + fr) * 80 + g * 16);
            s[0][nf] = __builtin_amdgcn_mfma_f32_16x16x32_bf16(ak, aq[0], zf, 0, 0, 0);
            s[1][nf] = __builtin_amdgcn_mfma_f32_16x16x32_bf16(ak, aq[1], zf, 0, 0, 0);
        }
        __builtin_amdgcn_s_setprio(0);

        // 4. exp2 + pack straight into PV A-fragment words (all in-register).
        //    word (nf&1)*2+0 = (r0,r1), +1 = (r2,r3); ks = nf>>1.
        u32x4 ppk[2][2];
        #pragma unroll
        for (int mf = 0; mf < 2; ++mf)
            #pragma unroll
            for (int nf = 0; nf < 4; ++nf) {
                float p_[4];
                #pragma unroll
                for (int r = 0; r < 4; ++r) p_[r] = __builtin_exp2f(s[mf][nf][r]);
                l_part[mf] += (p_[0] + p_[1]) + (p_[2] + p_[3]);
                ppk[mf][nf >> 1][(nf & 1) * 2 + 0] = cvt_pk_bf16(p_[0], p_[1]);
                ppk[mf][nf >> 1][(nf & 1) * 2 + 1] = cvt_pk_bf16(p_[2], p_[3]);
            }

        // 5. stage next K tile into the other buffer
        *(u32x4*)(kdst + (cur ^ 1) * 5120) = knx;

        // 6. PV(t): A = packed P (m = l = fr), B = V fragment (n = e)
        __builtin_amdgcn_s_setprio(1);
        #pragma unroll
        for (int ks = 0; ks < 2; ++ks) {
            bf16x8 ap0 = __builtin_bit_cast(bf16x8, ppk[0][ks]);
            bf16x8 ap1 = __builtin_bit_cast(bf16x8, ppk[1][ks]);
            #pragma unroll
            for (int nf = 0; nf < 4; ++nf) {
                o[0][nf] = __builtin_amdgcn_mfma_f32_16x16x32_bf16(ap0, vf[ks * 4 + nf], o[0][nf], 0, 0, 0);
                o[1][nf] = __builtin_amdgcn_mfma_f32_16x16x32_bf16(ap1, vf[ks * 4 + nf], o[1][nf], 0, 0, 0);
            }
        }
        __builtin_amdgcn_s_setprio(0);

        __syncthreads();   // kbuf[cur] reads done; kbuf[cur^1] write visible
    }

    // row-sum totals: lane holds l_part for l = mf*16 + fr; reduce over g
    #pragma unroll
    for (int mf = 0; mf < 2; ++mf) {
        l_part[mf] += __shfl_xor(l_part[mf], 16);
        l_part[mf] += __shfl_xor(l_part[mf], 32);
    }
    // output: o rows l = mf*16 + 4g + r, cols e = nf*16 + fr
    #pragma unroll
    for (int mf = 0; mf < 2; ++mf)
        #pragma unroll
        for (int r = 0; r < 4; ++r) {
            int l = l0 + mf * 16 + g * 4 + r;
            float tot = __shfl(l_part[mf], g * 4 + r);   // lane fr = 4g+r has it
            if (l < 2046) {
                float inv = 1.f / tot;
                #pragma unroll
                for (int nf = 0; nf < 4; ++nf)
                    attA[((i64)b * 2048 + l) * 1024 + h * 64 + nf * 16 + fr]
                        = f2b(o[mf][nf][r] * inv);
            }
        }
}

// ---------------------------------------------------------------------------
// launch
// ---------------------------------------------------------------------------
extern "C" void kernel_launch(void* const* d_in, const int* in_sizes, int n_in,
                              void* d_out, int out_size, void* d_ws, size_t ws_size,
                              hipStream_t stream) {
    const float* input = (const float*)d_in[0];  // [2046][4][1024]
    const float* w_kv  = (const float*)d_in[1];  // [1024][2048]
    const float* w_q   = (const float*)d_in[2];  // [512][1024]
    const float* b_q   = (const float*)d_in[3];  // [512]
    const float* w_out = (const float*)d_in[4];  // [1024][1024]
    const float* b_out = (const float*)d_in[5];  // [1024]
    float* out = (float*)d_out;                  // [2046][4][1024]

    char* W = (char*)d_ws;
    float* qp    = (float*)(W + 0);          // 8192x512 f32   (16 MB)
    u16* Xb      = (u16*)(W + 16777216);     // 8192x1024      (16 MB)
    u16* qb      = (u16*)(W + 33554432);     // 8192x512       (8 MB)
    u16* wq_b    = (u16*)(W + 41943040);     // 512x1024       (1 MB)
    u16* wkv_b   = (u16*)(W + 42991616);     // 1024x2048      (4 MB)
    u16* wout_b  = (u16*)(W + 47185920);     // 1024x1024      (2 MB)
    u16* kvA     = (u16*)(W + 49283072);     // 4x1536x2048    (24 MB)
    u16* kT      = (u16*)(W + 74448896);     // 4x16x1024x32   (4 MB)
    u16* vT      = (u16*)(W + 78643200);     // 4x16x64x1024   (8 MB)
    u16* attA    = (u16*)(W + 87031808);     // 4x2048x1024    (16 MB)

    dim3 blk(256);

    // bf16 conversions (independent)
    conv_pad<<<8192, blk, 0, stream>>>(input, Xb, 8184, 1024, 10, 1024);
    conv_pad<<<512,  blk, 0, stream>>>(w_q, wq_b, 512, 1024, 10, 1024);
    conv_pad<<<2048, blk, 0, stream>>>(w_kv, wkv_b, 1024, 2046, 11, 2048);
    conv_wout_perm<<<1024, blk, 0, stream>>>(w_out, wout_b);

    // q' = X @ w_q^T + b_q -> qp f32 + qb bf16(scaled)
    gemm_bf16<0><<<dim3(4, 64, 1), blk, 0, stream>>>(
        Xb, 0, wq_b, qp, b_q, qb, nullptr, 1024, 32, 8192);

    // combined kv A-panel (X + qp, transposed bf16)
    build_kvA<<<dim3(32, 24, 4), blk, 0, stream>>>(input, qp, kvA);

    // [v;k] = kvA @ wkv_b^T -> kT/vT bf16 (per b; vT in sigma2 layout)
    gemm_bf16<1><<<dim3(8, 12, 4), blk, 0, stream>>>(
        kvA, (i64)1536 * 2048, wkv_b, nullptr, nullptr, kT, vT, 2048, 64, 1536);

    // attention -> attA bf16 (swapped-QK, P-in-register, staged K)
    attn_mfma<<<dim3(1024), blk, 0, stream>>>(qb, kT, vT, attA);

    // out = attA @ wout_b^T + b_out (per b)
    gemm_bf16<2><<<dim3(8, 16, 4), blk, 0, stream>>>(
        attA, (i64)2048 * 1024, wout_b, out, b_out, nullptr, nullptr, 1024, 32, 2046);
}